// Round 7
// baseline (238.217 us; speedup 1.0000x reference)
//
#include <hip/hip_runtime.h>
#include <math.h>

// edge = a*box5(x) + b*box3(x) + c*x   (fused K5+K3 depthwise conv, zero pad)
// out  = abs(maxpool5(edge))           (maxpool pads with -inf; v-max then h-max)
//
// Block (256 thr, 4 waves) owns a 32-row strip of one plane. Stage 40 input
// rows (strip + 4-row halo each side) into LDS with materialized 2-px
// horizontal zero pads; one barrier; each wave sweeps an 8-row sub-strip in 16
// steps reading px[4i-2..4i+5] directly from LDS (4x ds_read_b64, no shuffles,
// no redundant global reads). Forward accumulation into 5 cyclic edge
// accumulators E and 5 cyclic vertical-max accumulators V (verbatim from R5/R6,
// absmax 0.03125). Shuffles only for the output horizontal 5-max.
// LDS 40x264x4 = 42.24 KB -> 3 blocks/CU. __launch_bounds__(256,3): VGPR cap
// ~170 >> natural need (~90) — R4 lesson: never cap below natural need.

#define STRIP   32
#define HALO    4
#define SROWS   (STRIP + 2*HALO)    // 40 staged rows
#define RSTRIDE 264                 // floats/row: [2..3]=Lpad, [4..259]=px, [260..261]=Rpad

typedef float vfloat4 __attribute__((ext_vector_type(4)));

__global__ __launch_bounds__(256, 3)
void edgepool_kernel(const float* __restrict__ xin, float* __restrict__ yout) {
    const int lane  = threadIdx.x & 63;
    const int wave  = threadIdx.x >> 6;
    const int blk   = blockIdx.x;                 // 0..4095
    const int plane = blk >> 3;                   // 0..511
    const int strip = blk & 7;                    // 0..7
    const int y0    = strip * STRIP;

    const float4* __restrict__ in4  = (const float4*)xin + (size_t)plane * 16384;
    vfloat4*      __restrict__ out4 = (vfloat4*)    yout + (size_t)plane * 16384;

    __shared__ float tile[SROWS * RSTRIDE];       // 42,240 B

    // ---- stage: 40 rows, 10 per wave; OOB rows written as zeros ----
#pragma unroll
    for (int k = 0; k < 10; ++k) {
        const int lr = wave + 4 * k;              // 0..39
        const int r  = y0 - HALO + lr;
        float4 v = make_float4(0.f, 0.f, 0.f, 0.f);
        if ((unsigned)r < 256u) v = in4[r * 64 + lane];
        *(float4*)&tile[lr * RSTRIDE + 4 + 4 * lane] = v;
        if (lane < 4)                             // zero the 2+2 horizontal pads
            tile[lr * RSTRIDE + ((lane < 2) ? 2 + lane : 258 + lane)] = 0.f;
    }
    __syncthreads();

    const float Wa = -0.01f, Wb = -0.19f, Wc = 2.2f;
    const float NINF = -INFINITY;

    float E[5][4];   // cyclic edge-row accumulators (conv partial sums)
    float V[5][4];   // cyclic vertical-5-max accumulators
#pragma unroll
    for (int k = 0; k < 5; ++k)
#pragma unroll
        for (int j = 0; j < 4; ++j) { E[k][j] = 0.f; V[k][j] = NINF; }

    // ---- sweep: wave handles output rows [y0+8*wave, y0+8*wave+8) ----
#pragma unroll
    for (int t = 0; t < 16; ++t) {
        const int lr = 8 * wave + t;              // staged row index
        const int r  = y0 - HALO + lr;            // global input row

        // 8-px window px[4i-2 .. 4i+5] straight from LDS (8B-aligned reads)
        const float2* p = (const float2*)&tile[lr * RSTRIDE + 2 + 4 * lane];
        const float2 A = p[0], B = p[1], C = p[2], D = p[3];
        const float lm2 = A.x, lm1 = A.y;
        const float v0 = B.x, v1 = B.y, v2 = C.x, v3 = C.y;
        const float rp0 = D.x, rp1 = D.y;

        // horizontal box sums
        const float s01 = v0 + v1, s23 = v2 + v3;
        const float h3[4] = { lm1 + s01, s01 + v2, v1 + s23, s23 + rp0 };
        const float h5[4] = { lm2 + lm1 + s01 + v2, lm1 + s01 + s23,
                              s01 + s23 + rp0,      v1 + s23 + rp0 + rp1 };
        const float vv[4] = { v0, v1, v2, v3 };

        // cyclic slots (compile-time after full unroll)
        const int e2 = (t + 2) % 5, e1 = (t + 1) % 5, e0 = t % 5,
                  em1 = (t + 4) % 5, em2 = (t + 3) % 5;

        // scatter this row into the 5 live edge accumulators
#pragma unroll
        for (int j = 0; j < 4; ++j) {
            E[e2][j]  = Wa * h5[j];                                      // init row r+2
            E[e1][j]  = fmaf(Wb, h3[j], fmaf(Wa, h5[j], E[e1][j]));
            E[e0][j]  = fmaf(Wc, vv[j], fmaf(Wb, h3[j], fmaf(Wa, h5[j], E[e0][j])));
            E[em1][j] = fmaf(Wb, h3[j], fmaf(Wa, h5[j], E[em1][j]));
            E[em2][j] = fmaf(Wa, h5[j], E[em2][j]);                      // completes row r-2
        }

        // edge row er = r-2 complete; -inf outside image for the maxpool
        const int  er  = r - 2;
        const bool ein = (unsigned)er < 256u;
        float e[4];
#pragma unroll
        for (int j = 0; j < 4; ++j) e[j] = ein ? E[em2][j] : NINF;

        // scatter edge row into the 5 live vertical-max accumulators
#pragma unroll
        for (int j = 0; j < 4; ++j) {
            V[e2][j]  = e[j];                          // init for output row er+2
            V[e1][j]  = fmaxf(V[e1][j], e[j]);
            V[e0][j]  = fmaxf(V[e0][j], e[j]);
            V[em1][j] = fmaxf(V[em1][j], e[j]);
            V[em2][j] = fmaxf(V[em2][j], e[j]);        // completes output row r-4
        }

        // output row o = r-4: horizontal 5-max of completed V row + abs + store
        if (t >= 8) {   // compile-time predicate after unroll
            const float m0 = V[em2][0], m1 = V[em2][1], m2 = V[em2][2], m3 = V[em2][3];
            float ml2 = __shfl(m2, lane - 1, 64);
            float ml1 = __shfl(m3, lane - 1, 64);
            float mr0 = __shfl(m0, lane + 1, 64);
            float mr1 = __shfl(m1, lane + 1, 64);
            ml2 = (lane == 0)  ? NINF : ml2;
            ml1 = (lane == 0)  ? NINF : ml1;
            mr0 = (lane == 63) ? NINF : mr0;
            mr1 = (lane == 63) ? NINF : mr1;
            vfloat4 ov;
            ov.x = fabsf(fmaxf(fmaxf(ml2, ml1), fmaxf(fmaxf(m0, m1), m2)));
            ov.y = fabsf(fmaxf(fmaxf(ml1, m0), fmaxf(fmaxf(m1, m2), m3)));
            ov.z = fabsf(fmaxf(fmaxf(m0, m1), fmaxf(fmaxf(m2, m3), mr0)));
            ov.w = fabsf(fmaxf(fmaxf(m1, m2), fmaxf(fmaxf(m3, mr0), mr1)));
            __builtin_nontemporal_store(ov, &out4[(r - 4) * 64 + lane]);
        }
    }
}

extern "C" void kernel_launch(void* const* d_in, const int* in_sizes, int n_in,
                              void* d_out, int out_size, void* d_ws, size_t ws_size,
                              hipStream_t stream) {
    const float* x   = (const float*)d_in[0];
    float*       out = (float*)d_out;
    // 512 planes x 8 strips = 4096 blocks x 256 threads.
    hipLaunchKernelGGL(edgepool_kernel, dim3(4096), dim3(256), 0, stream, x, out);
}

// Round 8
// 231.648 us; speedup vs baseline: 1.0284x; 1.0284x over previous
//
#include <hip/hip_runtime.h>
#include <math.h>
#include <stdint.h>

// edge = a*box5(x) + b*box3(x) + c*x   (fused K5+K3 depthwise conv, zero pad)
// out  = abs(maxpool5(edge))           (maxpool pads with -inf; v-max then h-max)
//
// Block (256 thr, 4 waves) owns a 32-row strip of one plane. Stage 40 rows
// (strip + 4 halo each side) into LDS via global_load_lds width-16 async DMA
// (dest = wave-uniform base + lane*16 -> exactly the HW pattern; no VGPR
// round-trip, not sinkable -> deep read MLP). Zero pads materialized in LDS.
// One barrier. Each wave sweeps an 8-row sub-strip in 16 steps reading
// 3x aligned ds_read_b128 (lane-stride 16B = canonical conflict-free pattern;
// R7's misaligned b64s were 8-way conflicted, 4.7M SQ_LDS_BANK_CONFLICT).
// asm "+v" pins keep the compiler from narrowing half-used L/R vectors back
// into conflicted b64 reads. E/V forward accumulation verbatim (absmax .03125).
// __launch_bounds__(256,3): VGPR cap ~170 >> need; R4 lesson: never cap below.

#define STRIP   32
#define HALO    4
#define SROWS   (STRIP + 2*HALO)    // 40 staged rows
#define RSTRIDE 264                 // dwords/row: [0..3]=Lpad, [4..259]=px, [260..263]=Rpad

typedef float vfloat4 __attribute__((ext_vector_type(4)));

__device__ __forceinline__ void lds_dma16(const void* g, void* l) {
#if __has_builtin(__builtin_amdgcn_global_load_lds)
    __builtin_amdgcn_global_load_lds(
        (const __attribute__((address_space(1))) uint32_t*)g,
        (__attribute__((address_space(3))) uint32_t*)l, 16, 0, 0);
#else
    // fallback: plain vector copy (per-lane slot)
    ((vfloat4*)l)[threadIdx.x & 63] = *((const vfloat4*)g + (threadIdx.x & 63));
#endif
}

__global__ __launch_bounds__(256, 3)
void edgepool_kernel(const float* __restrict__ xin, float* __restrict__ yout) {
    const int lane  = threadIdx.x & 63;
    const int wave  = threadIdx.x >> 6;
    const int blk   = blockIdx.x;                 // 0..4095
    const int plane = blk >> 3;                   // 0..511
    const int strip = blk & 7;                    // 0..7
    const int y0    = strip * STRIP;

    const float4* __restrict__ in4  = (const float4*)xin + (size_t)plane * 16384;
    vfloat4*      __restrict__ out4 = (vfloat4*)    yout + (size_t)plane * 16384;

    __shared__ float tile[SROWS * RSTRIDE];       // 42,240 B

    // ---- stage: 40 rows, 10 per wave, async DMA (16 B/lane, 1 KB/row) ----
#pragma unroll
    for (int k = 0; k < 10; ++k) {
        const int lr = wave + 4 * k;              // 0..39
        const int r  = y0 - HALO + lr;
        if ((unsigned)r < 256u) {
            lds_dma16(&in4[r * 64 + lane], &tile[lr * RSTRIDE + 4]);
        } else {                                  // OOB rows are conv zero-pad
            vfloat4 z = 0.f;
            *(vfloat4*)&tile[lr * RSTRIDE + 4 + 4 * lane] = z;
        }
    }
    // horizontal zero pads: dwords 0..3 and 260..263 of each row
    for (int i = threadIdx.x; i < SROWS * 8; i += 256) {
        const int row = i >> 3, sub = i & 7;
        tile[row * RSTRIDE + (sub < 4 ? sub : 256 + sub)] = 0.f;
    }
    __syncthreads();                              // drains DMA (vmcnt) + ds writes

    const float Wa = -0.01f, Wb = -0.19f, Wc = 2.2f;
    const float NINF = -INFINITY;

    float E[5][4];   // cyclic edge-row accumulators (conv partial sums)
    float V[5][4];   // cyclic vertical-5-max accumulators
#pragma unroll
    for (int k = 0; k < 5; ++k)
#pragma unroll
        for (int j = 0; j < 4; ++j) { E[k][j] = 0.f; V[k][j] = NINF; }

    // ---- sweep: wave handles output rows [y0+8*wave, y0+8*wave+8) ----
#pragma unroll
    for (int t = 0; t < 16; ++t) {
        const int lr   = 8 * wave + t;            // staged row index
        const int r    = y0 - HALO + lr;          // global input row
        const int base = lr * RSTRIDE + 4 + 4 * lane;

        // 3x aligned b128, lane-stride 16B: conflict-free
        vfloat4 Lh = *(const vfloat4*)&tile[base - 4];
        vfloat4 Ch = *(const vfloat4*)&tile[base];
        vfloat4 Rh = *(const vfloat4*)&tile[base + 4];
        asm("" : "+v"(Lh), "+v"(Rh));             // pin full width (no b64 narrowing)

        const float lm2 = Lh.z, lm1 = Lh.w;
        const float v0 = Ch.x, v1 = Ch.y, v2 = Ch.z, v3 = Ch.w;
        const float rp0 = Rh.x, rp1 = Rh.y;

        // horizontal box sums
        const float s01 = v0 + v1, s23 = v2 + v3;
        const float h3[4] = { lm1 + s01, s01 + v2, v1 + s23, s23 + rp0 };
        const float h5[4] = { lm2 + lm1 + s01 + v2, lm1 + s01 + s23,
                              s01 + s23 + rp0,      v1 + s23 + rp0 + rp1 };
        const float vv[4] = { v0, v1, v2, v3 };

        // cyclic slots (compile-time after full unroll)
        const int e2 = (t + 2) % 5, e1 = (t + 1) % 5, e0 = t % 5,
                  em1 = (t + 4) % 5, em2 = (t + 3) % 5;

        // scatter this row into the 5 live edge accumulators
#pragma unroll
        for (int j = 0; j < 4; ++j) {
            E[e2][j]  = Wa * h5[j];                                      // init row r+2
            E[e1][j]  = fmaf(Wb, h3[j], fmaf(Wa, h5[j], E[e1][j]));
            E[e0][j]  = fmaf(Wc, vv[j], fmaf(Wb, h3[j], fmaf(Wa, h5[j], E[e0][j])));
            E[em1][j] = fmaf(Wb, h3[j], fmaf(Wa, h5[j], E[em1][j]));
            E[em2][j] = fmaf(Wa, h5[j], E[em2][j]);                      // completes row r-2
        }

        // edge row er = r-2 complete; -inf outside image for the maxpool
        const int  er  = r - 2;
        const bool ein = (unsigned)er < 256u;
        float e[4];
#pragma unroll
        for (int j = 0; j < 4; ++j) e[j] = ein ? E[em2][j] : NINF;

        // scatter edge row into the 5 live vertical-max accumulators
#pragma unroll
        for (int j = 0; j < 4; ++j) {
            V[e2][j]  = e[j];                          // init for output row er+2
            V[e1][j]  = fmaxf(V[e1][j], e[j]);
            V[e0][j]  = fmaxf(V[e0][j], e[j]);
            V[em1][j] = fmaxf(V[em1][j], e[j]);
            V[em2][j] = fmaxf(V[em2][j], e[j]);        // completes output row r-4
        }

        // output row o = r-4: horizontal 5-max of completed V row + abs + store
        if (t >= 8) {   // compile-time predicate after unroll
            const float m0 = V[em2][0], m1 = V[em2][1], m2 = V[em2][2], m3 = V[em2][3];
            float ml2 = __shfl(m2, lane - 1, 64);
            float ml1 = __shfl(m3, lane - 1, 64);
            float mr0 = __shfl(m0, lane + 1, 64);
            float mr1 = __shfl(m1, lane + 1, 64);
            ml2 = (lane == 0)  ? NINF : ml2;
            ml1 = (lane == 0)  ? NINF : ml1;
            mr0 = (lane == 63) ? NINF : mr0;
            mr1 = (lane == 63) ? NINF : mr1;
            vfloat4 ov;
            ov.x = fabsf(fmaxf(fmaxf(ml2, ml1), fmaxf(fmaxf(m0, m1), m2)));
            ov.y = fabsf(fmaxf(fmaxf(ml1, m0), fmaxf(fmaxf(m1, m2), m3)));
            ov.z = fabsf(fmaxf(fmaxf(m0, m1), fmaxf(fmaxf(m2, m3), mr0)));
            ov.w = fabsf(fmaxf(fmaxf(m1, m2), fmaxf(fmaxf(m3, mr0), mr1)));
            __builtin_nontemporal_store(ov, &out4[(r - 4) * 64 + lane]);
        }
    }
}

extern "C" void kernel_launch(void* const* d_in, const int* in_sizes, int n_in,
                              void* d_out, int out_size, void* d_ws, size_t ws_size,
                              hipStream_t stream) {
    const float* x   = (const float*)d_in[0];
    float*       out = (float*)d_out;
    // 512 planes x 8 strips = 4096 blocks x 256 threads.
    hipLaunchKernelGGL(edgepool_kernel, dim3(4096), dim3(256), 0, stream, x, out);
}